// Round 1
// baseline (1101.946 us; speedup 1.0000x reference)
//
#include <hip/hip_runtime.h>
#include <math.h>

#define HH 128
#define WW 128
#define CCH 256
#define NHH 8
#define NPP 4
#define DDIM 32
#define HWW (HH * WW)
#define BB 2
#define MM (BB * HWW)

// ln(10000)/64
#define PE_LOG_STEP 0.14391156831f

__device__ __forceinline__ float pe_val(int c, int y, int x) {
    // channels 0..127: axis=y ; 128..255: axis=x ; even=sin, odd=cos
    int j = (c & 127) >> 1;
    float pos = (c < 128) ? (float)y : (float)x;
    float f = expf(-(float)j * PE_LOG_STEP);
    float s = pos * f;
    return (c & 1) ? cosf(s) : sinf(s);
}

// ---------------- transpose (B,C,HW) -> (B,HW,C) with input PE ----------------
__global__ __launch_bounds__(256) void transpose_pe_kernel(
    const float* __restrict__ ego, const float* __restrict__ in_scale,
    float* __restrict__ kt)
{
    __shared__ float tile[32][33];
    int b = blockIdx.z;
    int c0 = blockIdx.x * 32;
    int p0 = blockIdx.y * 32;
    int tx = threadIdx.x, ty = threadIdx.y; // (32,8)
    const float* egob = ego + (size_t)b * CCH * HWW;
    #pragma unroll
    for (int i = 0; i < 4; ++i) {
        int c = c0 + ty + i * 8;
        tile[ty + i * 8][tx] = egob[(size_t)c * HWW + p0 + tx];
    }
    __syncthreads();
    float isc = in_scale[0];
    float* ktb = kt + (size_t)b * HWW * CCH;
    #pragma unroll
    for (int i = 0; i < 4; ++i) {
        int p = p0 + ty + i * 8;
        int c = c0 + tx;
        int y = p >> 7, x = p & 127;
        ktb[(size_t)p * CCH + c] = tile[tx][ty + i * 8] + isc * pe_val(c, y, x);
    }
}

// ---------------- q = out + out_scale * pe_out ----------------
__global__ __launch_bounds__(256) void add_pe_kernel(
    const float* __restrict__ outbuf, const float* __restrict__ out_scale,
    float* __restrict__ q)
{
    int t = blockIdx.x * 256 + threadIdx.x;
    int c = t & 255;
    int p = (t >> 8) & (HWW - 1);
    int y = p >> 7, x = p & 127;
    q[t] = outbuf[t] + out_scale[0] * pe_val(c, y, x);
}

// ---------------- generic f32 GEMM: C = A(M,K) @ B(K,N) + bias (+ addsrc) ----
#define BM 64
#define BN 64
#define BK 16
__global__ __launch_bounds__(256) void gemm_bias_add(
    const float* __restrict__ A, const float* __restrict__ Bm,
    const float* __restrict__ bias, const float* __restrict__ addsrc,
    float* __restrict__ Cout, int M, int N, int K)
{
    __shared__ float As[BK][BM];
    __shared__ float Bs[BK][BN];
    int tid = threadIdx.x;
    int tx = tid & 15, ty = tid >> 4;
    int m0 = blockIdx.y * BM;
    int n0 = blockIdx.x * BN;
    float acc[4][4] = {};
    int la_m = tid >> 2;        // 0..63
    int la_k = (tid & 3) * 4;   // 0,4,8,12
    int lb_k = tid >> 4;        // 0..15
    int lb_n = (tid & 15) * 4;  // 0..60

    for (int k0 = 0; k0 < K; k0 += BK) {
        float4 a4 = *(const float4*)(A + (size_t)(m0 + la_m) * K + k0 + la_k);
        float4 b4 = make_float4(0.f, 0.f, 0.f, 0.f);
        if (n0 + lb_n < N)
            b4 = *(const float4*)(Bm + (size_t)(k0 + lb_k) * N + n0 + lb_n);
        __syncthreads();
        As[la_k + 0][la_m] = a4.x;
        As[la_k + 1][la_m] = a4.y;
        As[la_k + 2][la_m] = a4.z;
        As[la_k + 3][la_m] = a4.w;
        *(float4*)&Bs[lb_k][lb_n] = b4;
        __syncthreads();
        #pragma unroll
        for (int kk = 0; kk < BK; ++kk) {
            float4 av = *(const float4*)&As[kk][ty * 4];
            float4 bv = *(const float4*)&Bs[kk][tx * 4];
            float a_[4] = {av.x, av.y, av.z, av.w};
            float b_[4] = {bv.x, bv.y, bv.z, bv.w};
            #pragma unroll
            for (int i = 0; i < 4; ++i)
                #pragma unroll
                for (int j = 0; j < 4; ++j)
                    acc[i][j] += a_[i] * b_[j];
        }
    }
    #pragma unroll
    for (int i = 0; i < 4; ++i) {
        int row = m0 + ty * 4 + i;
        #pragma unroll
        for (int j = 0; j < 4; ++j) {
            int col = n0 + tx * 4 + j;
            if (col < N) {
                float v = acc[i][j] + bias[col];
                if (addsrc) v += addsrc[(size_t)row * N + col];
                Cout[(size_t)row * N + col] = v;
            }
        }
    }
}

// ---------------- softmax over last dim (NP=4) ----------------
__global__ __launch_bounds__(256) void softmax4_kernel(float* __restrict__ aw)
{
    int t = blockIdx.x * 256 + threadIdx.x; // t indexes (b,p,h)
    float4 v = *(float4*)(aw + (size_t)t * 4);
    float m = fmaxf(fmaxf(v.x, v.y), fmaxf(v.z, v.w));
    float ex = expf(v.x - m), ey = expf(v.y - m);
    float ez = expf(v.z - m), ew = expf(v.w - m);
    float r = 1.f / (ex + ey + ez + ew);
    *(float4*)(aw + (size_t)t * 4) = make_float4(ex * r, ey * r, ez * r, ew * r);
}

// ---------------- deformable bilinear sampling ----------------
// v: (B,HW,NH,D); offs: (B,HW,NH,NP,2); aw: (B,HW,NH,NP); attn: (B,HW,NH*D)
__global__ __launch_bounds__(256) void deform_kernel(
    const float* __restrict__ v, const float* __restrict__ offs,
    const float* __restrict__ aw, float* __restrict__ attn)
{
    int tid = threadIdx.x;
    int grp = tid >> 5;  // 8 groups of 32 lanes per block
    int d = tid & 31;
    long gid = (long)blockIdx.x * 8 + grp; // (b*HW+p)*NH + h
    int h = (int)(gid & 7);
    long bp = gid >> 3;       // b*HW + p
    int p = (int)(bp & (HWW - 1));
    int b = (int)(bp >> 14);
    int y = p >> 7, x = p & 127;
    float refx = (x + 0.5f) * (1.0f / WW);
    float refy = (y + 0.5f) * (1.0f / HH);
    const float* vb = v + (size_t)b * HWW * CCH;
    float acc = 0.f;
    #pragma unroll
    for (int pt = 0; pt < NPP; ++pt) {
        float ox = offs[gid * 8 + pt * 2 + 0];
        float oy = offs[gid * 8 + pt * 2 + 1];
        float wa = aw[gid * 4 + pt];
        float locx = refx + ox * (1.0f / WW);
        float locy = refy + oy * (1.0f / HH);
        float ix = locx * WW - 0.5f;
        float iy = locy * HH - 0.5f;
        float x0 = floorf(ix), y0 = floorf(iy);
        float wx1 = ix - x0, wy1 = iy - y0;
        float wx0 = 1.f - wx1, wy0 = 1.f - wy1;
        #pragma unroll
        for (int cy = 0; cy < 2; ++cy) {
            float yf = y0 + (float)cy;
            float wy = cy ? wy1 : wy0;
            bool vy = (yf >= 0.f) && (yf <= (float)(HH - 1));
            int yi = (int)fminf(fmaxf(yf, 0.f), (float)(HH - 1));
            #pragma unroll
            for (int cx = 0; cx < 2; ++cx) {
                float xf = x0 + (float)cx;
                float wxx = cx ? wx1 : wx0;
                bool vx = (xf >= 0.f) && (xf <= (float)(WW - 1));
                float wgt = (vx && vy) ? (wxx * wy * wa) : 0.f;
                int xi = (int)fminf(fmaxf(xf, 0.f), (float)(WW - 1));
                float vv = vb[(size_t)(yi * WW + xi) * CCH + h * DDIM + d];
                acc += wgt * vv;
            }
        }
    }
    attn[bp * CCH + h * DDIM + d] = acc;
}

extern "C" void kernel_launch(void* const* d_in, const int* in_sizes, int n_in,
                              void* d_out, int out_size, void* d_ws, size_t ws_size,
                              hipStream_t stream) {
    const float* ego       = (const float*)d_in[0];
    const float* conv_w    = (const float*)d_in[1];
    const float* conv_b    = (const float*)d_in[2];
    const float* in_scale  = (const float*)d_in[3];
    const float* out_scale = (const float*)d_in[4];
    const float* off_w     = (const float*)d_in[5];
    const float* off_b     = (const float*)d_in[6];
    const float* aw_w      = (const float*)d_in[7];
    const float* aw_b      = (const float*)d_in[8];
    const float* vp_w      = (const float*)d_in[9];
    const float* vp_b      = (const float*)d_in[10];
    const float* op_w      = (const float*)d_in[11];
    const float* op_b      = (const float*)d_in[12];
    float* out = (float*)d_out;

    float* ws   = (float*)d_ws;
    float* kt   = ws;                          // M*C
    float* q    = kt + (size_t)MM * CCH;       // M*C
    float* v    = q + (size_t)MM * CCH;        // M*C
    float* attn = v + (size_t)MM * CCH;        // M*C
    float* offs = attn + (size_t)MM * CCH;     // M*64
    float* aw   = offs + (size_t)MM * 64;      // M*32

    // key_tok = transpose(ego) + in_scale * PE
    transpose_pe_kernel<<<dim3(CCH / 32, HWW / 32, BB), dim3(32, 8), 0, stream>>>(
        ego, in_scale, kt);
    // out0 = key_tok @ conv_w + conv_b
    gemm_bias_add<<<dim3(CCH / BN, MM / BM), 256, 0, stream>>>(
        kt, conv_w, conv_b, nullptr, out, MM, CCH, CCH);

    for (int l = 0; l < 4; ++l) {
        // q = out + out_scale * PE (also the residual identity)
        add_pe_kernel<<<MM * CCH / 256, 256, 0, stream>>>(out, out_scale, q);
        // v = key_tok @ vp_w[l] + vp_b[l]
        gemm_bias_add<<<dim3(CCH / BN, MM / BM), 256, 0, stream>>>(
            kt, vp_w + (size_t)l * CCH * CCH, vp_b + l * CCH, nullptr, v, MM, CCH, CCH);
        // offs = q @ off_w[l] + off_b[l]   (N = 64)
        gemm_bias_add<<<dim3(1, MM / BM), 256, 0, stream>>>(
            q, off_w + (size_t)l * CCH * 64, off_b + l * 64, nullptr, offs, MM, 64, CCH);
        // aw = softmax(q @ aw_w[l] + aw_b[l])   (N = 32)
        gemm_bias_add<<<dim3(1, MM / BM), 256, 0, stream>>>(
            q, aw_w + (size_t)l * CCH * 32, aw_b + l * 32, nullptr, aw, MM, 32, CCH);
        softmax4_kernel<<<MM * NHH / 256, 256, 0, stream>>>(aw);
        // attn = deformable sampling
        deform_kernel<<<MM * NHH / 8, 256, 0, stream>>>(v, offs, aw, attn);
        // out = attn @ op_w[l] + op_b[l] + q
        gemm_bias_add<<<dim3(CCH / BN, MM / BM), 256, 0, stream>>>(
            attn, op_w + (size_t)l * CCH * CCH, op_b + l * CCH, q, out, MM, CCH, CCH);
    }
}

// Round 2
// 447.115 us; speedup vs baseline: 2.4646x; 2.4646x over previous
//
#include <hip/hip_runtime.h>
#include <math.h>

#define HH 128
#define WW 128
#define CCH 256
#define NHH 8
#define NPP 4
#define DDIM 32
#define HWW (HH * WW)
#define BB 2
#define MM (BB * HWW)
#define KK 256

typedef __attribute__((ext_vector_type(8))) __bf16 bf16x8;
typedef __attribute__((ext_vector_type(8))) short s16x8;
typedef __attribute__((ext_vector_type(4))) short s16x4;
typedef __attribute__((ext_vector_type(4))) float f32x4;

// ln(10000)/64
#define PE_LOG_STEP 0.14391156831f

__device__ __forceinline__ float pe_val(int c, int y, int x) {
    int j = (c & 127) >> 1;
    float pos = (c < 128) ? (float)y : (float)x;
    float f = expf(-(float)j * PE_LOG_STEP);
    float s = pos * f;
    return (c & 1) ? cosf(s) : sinf(s);
}

__device__ __forceinline__ short f2b(float f) {
    union { float f; unsigned u; } c; c.f = f;
    unsigned r = c.u + 0x7FFF + ((c.u >> 16) & 1);
    return (short)(r >> 16);
}

// ---------- convert big weights (K=256,N=256 row-major) -> W^T bf16 [N][K] ----------
__global__ __launch_bounds__(256) void convert_big_w(
    const float* __restrict__ conv_w, const float* __restrict__ vp_w,
    const float* __restrict__ op_w, short* __restrict__ wt)
{
    __shared__ float tile[32][33];
    int z = blockIdx.z;               // 0: conv, 1-4: vp, 5-8: op
    const float* src = (z == 0) ? conv_w
                     : (z <= 4) ? vp_w + (size_t)(z - 1) * KK * CCH
                                : op_w + (size_t)(z - 5) * KK * CCH;
    short* dst = wt + (size_t)z * KK * CCH;
    int k0 = blockIdx.x * 32, n0 = blockIdx.y * 32;
    int tx = threadIdx.x, ty = threadIdx.y;
    #pragma unroll
    for (int i = 0; i < 4; ++i)
        tile[ty + i * 8][tx] = src[(size_t)(k0 + ty + i * 8) * CCH + n0 + tx];
    __syncthreads();
    int t = ty * 32 + tx;
    int n_l = t >> 3, ks = (t & 7) * 4;
    s16x4 o;
    #pragma unroll
    for (int j = 0; j < 4; ++j) o[j] = f2b(tile[ks + j][n_l]);
    *(s16x4*)&dst[(size_t)(n0 + n_l) * KK + k0 + ks] = o;
}

// ---------- convert skinny weights: off_w (L,256,64), aw_w (L,256,32) ----------
__global__ __launch_bounds__(256) void convert_skinny_w(
    const float* __restrict__ off_w, const float* __restrict__ aw_w,
    short* __restrict__ wt_off, short* __restrict__ wt_aw)
{
    __shared__ float tile[32][33];
    int z = blockIdx.z;               // 0-3: off layer z (N=64), 4-7: aw (N=32)
    int N = (z < 4) ? 64 : 32;
    int n0 = blockIdx.y * 32;
    if (n0 >= N) return;              // uniform across block
    const float* src = (z < 4) ? off_w + (size_t)z * KK * 64
                               : aw_w + (size_t)(z - 4) * KK * 32;
    short* dst = (z < 4) ? wt_off + (size_t)z * 64 * KK
                         : wt_aw + (size_t)(z - 4) * 32 * KK;
    int k0 = blockIdx.x * 32;
    int tx = threadIdx.x, ty = threadIdx.y;
    #pragma unroll
    for (int i = 0; i < 4; ++i)
        tile[ty + i * 8][tx] = src[(size_t)(k0 + ty + i * 8) * N + n0 + tx];
    __syncthreads();
    int t = ty * 32 + tx;
    int n_l = t >> 3, ks = (t & 7) * 4;
    s16x4 o;
    #pragma unroll
    for (int j = 0; j < 4; ++j) o[j] = f2b(tile[ks + j][n_l]);
    *(s16x4*)&dst[(size_t)(n0 + n_l) * KK + k0 + ks] = o;
}

// ---------- transpose (B,C,HW) -> kt bf16 (B,HW,C) with input PE ----------
__global__ __launch_bounds__(256) void transpose_pe_kernel(
    const float* __restrict__ ego, const float* __restrict__ in_scale,
    short* __restrict__ ktb)
{
    __shared__ float tile[32][33];    // [c_local][p_local]
    int b = blockIdx.z;
    int c0 = blockIdx.x * 32;
    int p0 = blockIdx.y * 32;
    int tx = threadIdx.x, ty = threadIdx.y; // (32,8)
    const float* egob = ego + (size_t)b * CCH * HWW;
    #pragma unroll
    for (int i = 0; i < 4; ++i)
        tile[ty + i * 8][tx] = egob[(size_t)(c0 + ty + i * 8) * HWW + p0 + tx];
    __syncthreads();
    float isc = in_scale[0];
    int t = ty * 32 + tx;
    int p_l = t >> 3, cs = (t & 7) * 4;
    int p = p0 + p_l;
    int y = p >> 7, x = p & 127;
    s16x4 o;
    #pragma unroll
    for (int j = 0; j < 4; ++j) {
        int c = c0 + cs + j;
        o[j] = f2b(tile[cs + j][p_l] + isc * pe_val(c, y, x));
    }
    *(s16x4*)&ktb[((size_t)b * HWW + p) * CCH + c0 + cs] = o;
}

// ---------- q = out + out_scale * pe_out : f32 + bf16 copies ----------
__global__ __launch_bounds__(256) void add_pe_kernel(
    const float* __restrict__ outbuf, const float* __restrict__ out_scale,
    float* __restrict__ qf, short* __restrict__ qb)
{
    int t = blockIdx.x * 256 + threadIdx.x;
    int m = t >> 5;
    int cs = (t & 31) * 8;
    int p = m & (HWW - 1);
    int y = p >> 7, x = p & 127;
    float4 a = *(const float4*)(outbuf + (size_t)m * CCH + cs);
    float4 b = *(const float4*)(outbuf + (size_t)m * CCH + cs + 4);
    float vals[8] = {a.x, a.y, a.z, a.w, b.x, b.y, b.z, b.w};
    float sc = out_scale[0];
    s16x8 ob;
    #pragma unroll
    for (int j = 0; j < 8; ++j) {
        float vv = vals[j] + sc * pe_val(cs + j, y, x);
        vals[j] = vv;
        ob[j] = f2b(vv);
    }
    *(float4*)(qf + (size_t)m * CCH + cs) = make_float4(vals[0], vals[1], vals[2], vals[3]);
    *(float4*)(qf + (size_t)m * CCH + cs + 4) = make_float4(vals[4], vals[5], vals[6], vals[7]);
    *(s16x8*)&qb[(size_t)m * CCH + cs] = ob;
}

// ---------- bf16 MFMA GEMM: C(M,N) = A(M,256)bf16 @ B^T(N,256)bf16 + bias (+res) ----------
// LDS layout: row r of a tile holds 8 slots of 8 bf16; slot s stored at (s ^ (r&7)).
__device__ __forceinline__ const short* lds_frag(const short* base, int r, int s) {
    return base + r * 64 + ((s ^ (r & 7)) * 8);
}

template<int BN, int WM, int WN, bool RES>
__global__ __launch_bounds__(256) void mfma_gemm(
    const short* __restrict__ A, const short* __restrict__ Bt,
    const float* __restrict__ bias, const float* __restrict__ res,
    float* __restrict__ C, int Ntot)
{
    constexpr int MF = WM / 16, NF = WN / 16;
    constexpr int WAVES_N = BN / WN;
    constexpr int BTASK = BN / 32;
    __shared__ short As[128 * 64];
    __shared__ short Bs[BN * 64];
    int tid = threadIdx.x;
    int w = tid >> 6, lane = tid & 63;
    int g = lane >> 4, l16 = lane & 15;
    int wr = w / WAVES_N, wc = w % WAVES_N;
    int m0 = blockIdx.y * 128;
    int n0 = blockIdx.x * BN;

    f32x4 acc[MF][NF] = {};
    s16x8 ra[4];
    s16x8 rb[BTASK];

    // prologue: load k-step 0 into regs
    #pragma unroll
    for (int i = 0; i < 4; ++i) {
        int task = tid + i * 256; int r = task >> 3, s = task & 7;
        ra[i] = *(const s16x8*)(A + (size_t)(m0 + r) * KK + s * 8);
    }
    #pragma unroll
    for (int i = 0; i < BTASK; ++i) {
        int task = tid + i * 256; int r = task >> 3, s = task & 7;
        rb[i] = *(const s16x8*)(Bt + (size_t)(n0 + r) * KK + s * 8);
    }

    for (int ks = 0; ks < 4; ++ks) {
        __syncthreads();
        #pragma unroll
        for (int i = 0; i < 4; ++i) {
            int task = tid + i * 256; int r = task >> 3, s = task & 7;
            *(s16x8*)&As[r * 64 + ((s ^ (r & 7)) * 8)] = ra[i];
        }
        #pragma unroll
        for (int i = 0; i < BTASK; ++i) {
            int task = tid + i * 256; int r = task >> 3, s = task & 7;
            *(s16x8*)&Bs[r * 64 + ((s ^ (r & 7)) * 8)] = rb[i];
        }
        __syncthreads();
        if (ks < 3) {
            #pragma unroll
            for (int i = 0; i < 4; ++i) {
                int task = tid + i * 256; int r = task >> 3, s = task & 7;
                ra[i] = *(const s16x8*)(A + (size_t)(m0 + r) * KK + (ks + 1) * 64 + s * 8);
            }
            #pragma unroll
            for (int i = 0; i < BTASK; ++i) {
                int task = tid + i * 256; int r = task >> 3, s = task & 7;
                rb[i] = *(const s16x8*)(Bt + (size_t)(n0 + r) * KK + (ks + 1) * 64 + s * 8);
            }
        }
        #pragma unroll
        for (int kh = 0; kh < 2; ++kh) {
            bf16x8 af[MF], bfr[NF];
            #pragma unroll
            for (int mf = 0; mf < MF; ++mf)
                af[mf] = *(const bf16x8*)lds_frag(As, wr * WM + mf * 16 + l16, kh * 4 + g);
            #pragma unroll
            for (int nf = 0; nf < NF; ++nf)
                bfr[nf] = *(const bf16x8*)lds_frag(Bs, wc * WN + nf * 16 + l16, kh * 4 + g);
            #pragma unroll
            for (int mf = 0; mf < MF; ++mf)
                #pragma unroll
                for (int nf = 0; nf < NF; ++nf)
                    acc[mf][nf] = __builtin_amdgcn_mfma_f32_16x16x32_bf16(
                        af[mf], bfr[nf], acc[mf][nf], 0, 0, 0);
        }
    }

    // epilogue: C[row][col], row = (lane>>4)*4 + reg, col = lane&15 (verified m89)
    #pragma unroll
    for (int mf = 0; mf < MF; ++mf) {
        #pragma unroll
        for (int nf = 0; nf < NF; ++nf) {
            int col = n0 + wc * WN + nf * 16 + l16;
            #pragma unroll
            for (int j = 0; j < 4; ++j) {
                int row = m0 + wr * WM + mf * 16 + g * 4 + j;
                float vv = acc[mf][nf][j] + bias[col];
                if (RES) vv += res[(size_t)row * Ntot + col];
                C[(size_t)row * Ntot + col] = vv;
            }
        }
    }
}

// ---------- softmax over last dim (NP=4) ----------
__global__ __launch_bounds__(256) void softmax4_kernel(float* __restrict__ aw)
{
    int t = blockIdx.x * 256 + threadIdx.x;
    float4 v = *(float4*)(aw + (size_t)t * 4);
    float m = fmaxf(fmaxf(v.x, v.y), fmaxf(v.z, v.w));
    float ex = expf(v.x - m), ey = expf(v.y - m);
    float ez = expf(v.z - m), ew = expf(v.w - m);
    float r = 1.f / (ex + ey + ez + ew);
    *(float4*)(aw + (size_t)t * 4) = make_float4(ex * r, ey * r, ez * r, ew * r);
}

// ---------- deformable bilinear sampling -> attn bf16 ----------
__global__ __launch_bounds__(256) void deform_kernel(
    const float* __restrict__ v, const float* __restrict__ offs,
    const float* __restrict__ aw, short* __restrict__ attnb)
{
    int tid = threadIdx.x;
    int grp = tid >> 5;
    int d = tid & 31;
    long gid = (long)blockIdx.x * 8 + grp; // (b*HW+p)*NH + h
    int h = (int)(gid & 7);
    long bp = gid >> 3;
    int p = (int)(bp & (HWW - 1));
    int b = (int)(bp >> 14);
    int y = p >> 7, x = p & 127;
    float refx = (x + 0.5f) * (1.0f / WW);
    float refy = (y + 0.5f) * (1.0f / HH);
    const float* vb = v + (size_t)b * HWW * CCH;
    float acc = 0.f;
    #pragma unroll
    for (int pt = 0; pt < NPP; ++pt) {
        float ox = offs[gid * 8 + pt * 2 + 0];
        float oy = offs[gid * 8 + pt * 2 + 1];
        float wa = aw[gid * 4 + pt];
        float locx = refx + ox * (1.0f / WW);
        float locy = refy + oy * (1.0f / HH);
        float ix = locx * WW - 0.5f;
        float iy = locy * HH - 0.5f;
        float x0 = floorf(ix), y0 = floorf(iy);
        float wx1 = ix - x0, wy1 = iy - y0;
        float wx0 = 1.f - wx1, wy0 = 1.f - wy1;
        #pragma unroll
        for (int cy = 0; cy < 2; ++cy) {
            float yf = y0 + (float)cy;
            float wy = cy ? wy1 : wy0;
            bool vy = (yf >= 0.f) && (yf <= (float)(HH - 1));
            int yi = (int)fminf(fmaxf(yf, 0.f), (float)(HH - 1));
            #pragma unroll
            for (int cx = 0; cx < 2; ++cx) {
                float xf = x0 + (float)cx;
                float wxx = cx ? wx1 : wx0;
                bool vx = (xf >= 0.f) && (xf <= (float)(WW - 1));
                float wgt = (vx && vy) ? (wxx * wy * wa) : 0.f;
                int xi = (int)fminf(fmaxf(xf, 0.f), (float)(WW - 1));
                float vv = vb[(size_t)(yi * WW + xi) * CCH + h * DDIM + d];
                acc += wgt * vv;
            }
        }
    }
    attnb[bp * CCH + h * DDIM + d] = f2b(acc);
}

extern "C" void kernel_launch(void* const* d_in, const int* in_sizes, int n_in,
                              void* d_out, int out_size, void* d_ws, size_t ws_size,
                              hipStream_t stream) {
    const float* ego       = (const float*)d_in[0];
    const float* conv_w    = (const float*)d_in[1];
    const float* conv_b    = (const float*)d_in[2];
    const float* in_scale  = (const float*)d_in[3];
    const float* out_scale = (const float*)d_in[4];
    const float* off_w     = (const float*)d_in[5];
    const float* off_b     = (const float*)d_in[6];
    const float* aw_w      = (const float*)d_in[7];
    const float* aw_b      = (const float*)d_in[8];
    const float* vp_w      = (const float*)d_in[9];
    const float* vp_b      = (const float*)d_in[10];
    const float* op_w      = (const float*)d_in[11];
    const float* op_b      = (const float*)d_in[12];
    float* out = (float*)d_out;

    float* qf   = (float*)d_ws;                 // M*256 f32
    float* v    = qf + (size_t)MM * CCH;        // M*256 f32
    float* offs = v + (size_t)MM * CCH;         // M*64
    float* aw   = offs + (size_t)MM * 64;       // M*32
    short* ktb    = (short*)(aw + (size_t)MM * 32);   // M*256 bf16
    short* qb     = ktb + (size_t)MM * CCH;
    short* attnb  = qb + (size_t)MM * CCH;
    short* wt_big = attnb + (size_t)MM * CCH;   // 9 * 256*256
    short* wt_off = wt_big + 9 * KK * CCH;      // 4 * 64*256
    short* wt_aw  = wt_off + 4 * 64 * KK;       // 4 * 32*256

    convert_big_w<<<dim3(8, 8, 9), dim3(32, 8), 0, stream>>>(conv_w, vp_w, op_w, wt_big);
    convert_skinny_w<<<dim3(8, 2, 8), dim3(32, 8), 0, stream>>>(off_w, aw_w, wt_off, wt_aw);
    transpose_pe_kernel<<<dim3(8, 512, 2), dim3(32, 8), 0, stream>>>(ego, in_scale, ktb);

    // out0 = key_tok @ conv_w + conv_b
    mfma_gemm<128, 64, 64, false><<<dim3(2, 256), 256, 0, stream>>>(
        ktb, wt_big, conv_b, nullptr, out, CCH);

    for (int l = 0; l < 4; ++l) {
        add_pe_kernel<<<MM * 32 / 256, 256, 0, stream>>>(out, out_scale, qf, qb);
        mfma_gemm<128, 64, 64, false><<<dim3(2, 256), 256, 0, stream>>>(
            ktb, wt_big + (size_t)(1 + l) * KK * CCH, vp_b + l * CCH, nullptr, v, CCH);
        mfma_gemm<64, 32, 64, false><<<dim3(1, 256), 256, 0, stream>>>(
            qb, wt_off + (size_t)l * 64 * KK, off_b + l * 64, nullptr, offs, 64);
        mfma_gemm<32, 32, 32, false><<<dim3(1, 256), 256, 0, stream>>>(
            qb, wt_aw + (size_t)l * 32 * KK, aw_b + l * 32, nullptr, aw, 32);
        softmax4_kernel<<<MM * NHH / 256, 256, 0, stream>>>(aw);
        deform_kernel<<<MM * NHH / 8, 256, 0, stream>>>(v, offs, aw, attnb);
        mfma_gemm<128, 64, 64, true><<<dim3(2, 256), 256, 0, stream>>>(
            attnb, wt_big + (size_t)(5 + l) * KK * CCH, op_b + l * CCH, qf, out, CCH);
    }
}

// Round 3
// 294.495 us; speedup vs baseline: 3.7418x; 1.5182x over previous
//
#include <hip/hip_runtime.h>
#include <math.h>

#define HH 128
#define WW 128
#define CCH 256
#define NHH 8
#define NPP 4
#define DDIM 32
#define HWW (HH * WW)
#define BB 2
#define MM (BB * HWW)
#define KK 256

typedef __attribute__((ext_vector_type(8))) __bf16 bf16x8;
typedef __attribute__((ext_vector_type(8))) short s16x8;
typedef __attribute__((ext_vector_type(4))) short s16x4;
typedef __attribute__((ext_vector_type(4))) float f32x4;

// ln(10000)/64
#define PE_LOG_STEP 0.14391156831f

__device__ __forceinline__ float pe_val(int c, int y, int x) {
    int j = (c & 127) >> 1;
    float pos = (c < 128) ? (float)y : (float)x;
    float f = expf(-(float)j * PE_LOG_STEP);
    float s = pos * f;
    return (c & 1) ? cosf(s) : sinf(s);
}

__device__ __forceinline__ short f2b(float f) {
    union { float f; unsigned u; } c; c.f = f;
    unsigned r = c.u + 0x7FFF + ((c.u >> 16) & 1);
    return (short)(r >> 16);
}

__device__ __forceinline__ float b2f(short s) {
    union { unsigned u; float f; } c;
    c.u = ((unsigned)(unsigned short)s) << 16;
    return c.f;
}

// ---------- scaled output-PE table: pe[p*256+c] = out_scale * pe_val(c,y,x) ----------
__global__ __launch_bounds__(256) void pe_table_kernel(
    const float* __restrict__ out_scale, float* __restrict__ pe)
{
    int t = blockIdx.x * 256 + threadIdx.x;   // pair index: HWW*128 total
    int cp = t & 127;                         // channel pair 0..127
    int p = t >> 7;
    int y = p >> 7, x = p & 127;
    int c2 = cp * 2;
    int j = (c2 & 127) >> 1;
    float pos = (c2 < 128) ? (float)y : (float)x;
    float f = expf(-(float)j * PE_LOG_STEP);
    float s, c;
    __sincosf(pos * f, &s, &c);
    float sc = out_scale[0];
    pe[(size_t)p * CCH + c2] = sc * s;
    pe[(size_t)p * CCH + c2 + 1] = sc * c;
}

// ---------- convert big weights (K=256,N=256 row-major) -> W^T bf16 [N][K] ----------
__global__ __launch_bounds__(256) void convert_big_w(
    const float* __restrict__ conv_w, const float* __restrict__ vp_w,
    const float* __restrict__ op_w, short* __restrict__ wt)
{
    __shared__ float tile[32][33];
    int z = blockIdx.z;               // 0: conv, 1-4: vp, 5-8: op
    const float* src = (z == 0) ? conv_w
                     : (z <= 4) ? vp_w + (size_t)(z - 1) * KK * CCH
                                : op_w + (size_t)(z - 5) * KK * CCH;
    short* dst = wt + (size_t)z * KK * CCH;
    int k0 = blockIdx.x * 32, n0 = blockIdx.y * 32;
    int tx = threadIdx.x, ty = threadIdx.y;
    #pragma unroll
    for (int i = 0; i < 4; ++i)
        tile[ty + i * 8][tx] = src[(size_t)(k0 + ty + i * 8) * CCH + n0 + tx];
    __syncthreads();
    int t = ty * 32 + tx;
    int n_l = t >> 3, ks = (t & 7) * 4;
    s16x4 o;
    #pragma unroll
    for (int j = 0; j < 4; ++j) o[j] = f2b(tile[ks + j][n_l]);
    *(s16x4*)&dst[(size_t)(n0 + n_l) * KK + k0 + ks] = o;
}

// ---------- convert + concat skinny weights -> wt[L][96][256], bias_cat[L][96] ----------
__global__ __launch_bounds__(256) void convert_offaw_w(
    const float* __restrict__ off_w, const float* __restrict__ aw_w,
    const float* __restrict__ off_b, const float* __restrict__ aw_b,
    short* __restrict__ wt, float* __restrict__ bias_cat)
{
    __shared__ float tile[32][33];
    int l = blockIdx.z;
    int nt = blockIdx.y;              // 0,1: off cols nt*32 ; 2: aw cols 0..31
    int k0 = blockIdx.x * 32;
    const float* src; int N, ncol0;
    if (nt < 2) { src = off_w + (size_t)l * KK * 64; N = 64; ncol0 = nt * 32; }
    else        { src = aw_w + (size_t)l * KK * 32; N = 32; ncol0 = 0; }
    int tx = threadIdx.x, ty = threadIdx.y;
    #pragma unroll
    for (int i = 0; i < 4; ++i)
        tile[ty + i * 8][tx] = src[(size_t)(k0 + ty + i * 8) * N + ncol0 + tx];
    __syncthreads();
    int t = ty * 32 + tx;
    int n_l = t >> 3, ks = (t & 7) * 4;
    s16x4 o;
    #pragma unroll
    for (int j = 0; j < 4; ++j) o[j] = f2b(tile[ks + j][n_l]);
    *(s16x4*)&wt[((size_t)l * 96 + nt * 32 + n_l) * KK + k0 + ks] = o;
    if (blockIdx.x == 0 && t < 32) {
        int col = nt * 32 + t;
        bias_cat[l * 96 + col] = (nt < 2) ? off_b[l * 64 + ncol0 + t]
                                          : aw_b[l * 32 + t];
    }
}

// ---------- transpose (B,C,HW) -> kt bf16 (B,HW,C) with input PE ----------
__global__ __launch_bounds__(256) void transpose_pe_kernel(
    const float* __restrict__ ego, const float* __restrict__ in_scale,
    short* __restrict__ ktb)
{
    __shared__ float tile[32][33];    // [c_local][p_local]
    int b = blockIdx.z;
    int c0 = blockIdx.x * 32;
    int p0 = blockIdx.y * 32;
    int tx = threadIdx.x, ty = threadIdx.y; // (32,8)
    const float* egob = ego + (size_t)b * CCH * HWW;
    #pragma unroll
    for (int i = 0; i < 4; ++i)
        tile[ty + i * 8][tx] = egob[(size_t)(c0 + ty + i * 8) * HWW + p0 + tx];
    __syncthreads();
    float isc = in_scale[0];
    int t = ty * 32 + tx;
    int p_l = t >> 3, cs = (t & 7) * 4;
    int p = p0 + p_l;
    int y = p >> 7, x = p & 127;
    s16x4 o;
    #pragma unroll
    for (int j = 0; j < 4; ++j) {
        int c = c0 + cs + j;
        o[j] = f2b(tile[cs + j][p_l] + isc * pe_val(c, y, x));
    }
    *(s16x4*)&ktb[((size_t)b * HWW + p) * CCH + c0 + cs] = o;
}

// ---------- bf16 MFMA GEMM ----------
// OM 0: write f32 C (+res).  OM 1: write qf = acc+bias(+res)+pe  and qb bf16.
// OM 2: write bf16 C.
__device__ __forceinline__ const short* lds_frag(const short* base, int r, int s) {
    return base + r * 64 + ((s ^ (r & 7)) * 8);
}

template<int BN, int WM, int WN, bool RES, int OM>
__global__ __launch_bounds__(256) void mfma_gemm(
    const short* __restrict__ A, const short* __restrict__ Bt,
    const float* __restrict__ bias, const float* __restrict__ res,
    const float* __restrict__ pe, float* __restrict__ Cf,
    short* __restrict__ Cb, int Ntot)
{
    constexpr int MF = WM / 16, NF = WN / 16;
    constexpr int WAVES_N = BN / WN;
    constexpr int BTASK = BN / 32;
    __shared__ short As[128 * 64];
    __shared__ short Bs[BN * 64];
    int tid = threadIdx.x;
    int w = tid >> 6, lane = tid & 63;
    int g = lane >> 4, l16 = lane & 15;
    int wr = w / WAVES_N, wc = w % WAVES_N;
    int m0 = blockIdx.y * 128;
    int n0 = blockIdx.x * BN;

    f32x4 acc[MF][NF] = {};
    s16x8 ra[4];
    s16x8 rb[BTASK];

    #pragma unroll
    for (int i = 0; i < 4; ++i) {
        int task = tid + i * 256; int r = task >> 3, s = task & 7;
        ra[i] = *(const s16x8*)(A + (size_t)(m0 + r) * KK + s * 8);
    }
    #pragma unroll
    for (int i = 0; i < BTASK; ++i) {
        int task = tid + i * 256; int r = task >> 3, s = task & 7;
        rb[i] = *(const s16x8*)(Bt + (size_t)(n0 + r) * KK + s * 8);
    }

    for (int ks = 0; ks < 4; ++ks) {
        __syncthreads();
        #pragma unroll
        for (int i = 0; i < 4; ++i) {
            int task = tid + i * 256; int r = task >> 3, s = task & 7;
            *(s16x8*)&As[r * 64 + ((s ^ (r & 7)) * 8)] = ra[i];
        }
        #pragma unroll
        for (int i = 0; i < BTASK; ++i) {
            int task = tid + i * 256; int r = task >> 3, s = task & 7;
            *(s16x8*)&Bs[r * 64 + ((s ^ (r & 7)) * 8)] = rb[i];
        }
        __syncthreads();
        if (ks < 3) {
            #pragma unroll
            for (int i = 0; i < 4; ++i) {
                int task = tid + i * 256; int r = task >> 3, s = task & 7;
                ra[i] = *(const s16x8*)(A + (size_t)(m0 + r) * KK + (ks + 1) * 64 + s * 8);
            }
            #pragma unroll
            for (int i = 0; i < BTASK; ++i) {
                int task = tid + i * 256; int r = task >> 3, s = task & 7;
                rb[i] = *(const s16x8*)(Bt + (size_t)(n0 + r) * KK + (ks + 1) * 64 + s * 8);
            }
        }
        #pragma unroll
        for (int kh = 0; kh < 2; ++kh) {
            bf16x8 af[MF], bfr[NF];
            #pragma unroll
            for (int mf = 0; mf < MF; ++mf)
                af[mf] = *(const bf16x8*)lds_frag(As, wr * WM + mf * 16 + l16, kh * 4 + g);
            #pragma unroll
            for (int nf = 0; nf < NF; ++nf)
                bfr[nf] = *(const bf16x8*)lds_frag(Bs, wc * WN + nf * 16 + l16, kh * 4 + g);
            #pragma unroll
            for (int mf = 0; mf < MF; ++mf)
                #pragma unroll
                for (int nf = 0; nf < NF; ++nf)
                    acc[mf][nf] = __builtin_amdgcn_mfma_f32_16x16x32_bf16(
                        af[mf], bfr[nf], acc[mf][nf], 0, 0, 0);
        }
    }

    // C[row][col]: row = (lane>>4)*4 + reg, col = lane&15 (verified m89)
    #pragma unroll
    for (int mf = 0; mf < MF; ++mf) {
        #pragma unroll
        for (int nf = 0; nf < NF; ++nf) {
            int col = n0 + wc * WN + nf * 16 + l16;
            float bv = bias[col];
            #pragma unroll
            for (int j = 0; j < 4; ++j) {
                int row = m0 + wr * WM + mf * 16 + g * 4 + j;
                float vv = acc[mf][nf][j] + bv;
                if (RES) vv += res[(size_t)row * Ntot + col];
                if (OM == 0) {
                    Cf[(size_t)row * Ntot + col] = vv;
                } else if (OM == 1) {
                    int p = row & (HWW - 1);
                    float qn = vv + pe[(size_t)p * CCH + col];
                    Cf[(size_t)row * Ntot + col] = qn;
                    Cb[(size_t)row * Ntot + col] = f2b(qn);
                } else {
                    Cb[(size_t)row * Ntot + col] = f2b(vv);
                }
            }
        }
    }
}

// ---------- deformable sampling + inline softmax ----------
// vb16: (B,HW,256) bf16; scores: (B*HW, 96) = [offs 64 | aw 32]; attnb: (B*HW,256) bf16
__global__ __launch_bounds__(256) void deform_kernel(
    const short* __restrict__ vb16, const float* __restrict__ scores,
    short* __restrict__ attnb)
{
    int tid = threadIdx.x;
    long gid = (long)blockIdx.x * 32 + (tid >> 3); // (b*HW+p)*NH + h
    int dl = (tid & 7) * 4;
    int h = (int)(gid & 7);
    long bp = gid >> 3;
    int p = (int)(bp & (HWW - 1));
    int b = (int)(bp >> 14);
    int y = p >> 7, x = p & 127;
    const float* srow = scores + bp * 96;
    // softmax over the 4 raw attention scores of this head
    float s0 = srow[64 + h * 4 + 0];
    float s1 = srow[64 + h * 4 + 1];
    float s2 = srow[64 + h * 4 + 2];
    float s3 = srow[64 + h * 4 + 3];
    float mx = fmaxf(fmaxf(s0, s1), fmaxf(s2, s3));
    float ea[4] = {expf(s0 - mx), expf(s1 - mx), expf(s2 - mx), expf(s3 - mx)};
    float inv = 1.f / (ea[0] + ea[1] + ea[2] + ea[3]);
    const short* vbase = vb16 + (size_t)b * HWW * CCH + h * DDIM + dl;
    float a0 = 0.f, a1 = 0.f, a2 = 0.f, a3 = 0.f;
    #pragma unroll
    for (int pt = 0; pt < NPP; ++pt) {
        float ox = srow[h * 8 + pt * 2 + 0];
        float oy = srow[h * 8 + pt * 2 + 1];
        float wa = ea[pt] * inv;
        float ix = (float)x + ox;       // grid_sample chain collapses to x+ox
        float iy = (float)y + oy;
        float x0 = floorf(ix), y0 = floorf(iy);
        float wx1 = ix - x0, wy1 = iy - y0;
        float wx0 = 1.f - wx1, wy0 = 1.f - wy1;
        #pragma unroll
        for (int cy = 0; cy < 2; ++cy) {
            float yf = y0 + (float)cy;
            float wy = cy ? wy1 : wy0;
            bool vy = (yf >= 0.f) && (yf <= (float)(HH - 1));
            int yi = (int)fminf(fmaxf(yf, 0.f), (float)(HH - 1));
            #pragma unroll
            for (int cx = 0; cx < 2; ++cx) {
                float xf = x0 + (float)cx;
                float wxx = cx ? wx1 : wx0;
                bool vx = (xf >= 0.f) && (xf <= (float)(WW - 1));
                float wgt = (vx && vy) ? (wxx * wy * wa) : 0.f;
                int xi = (int)fminf(fmaxf(xf, 0.f), (float)(WW - 1));
                s16x4 vv = *(const s16x4*)(vbase + (size_t)(yi * WW + xi) * CCH);
                a0 += wgt * b2f(vv[0]);
                a1 += wgt * b2f(vv[1]);
                a2 += wgt * b2f(vv[2]);
                a3 += wgt * b2f(vv[3]);
            }
        }
    }
    s16x4 o;
    o[0] = f2b(a0); o[1] = f2b(a1); o[2] = f2b(a2); o[3] = f2b(a3);
    *(s16x4*)&attnb[bp * CCH + h * DDIM + dl] = o;
}

extern "C" void kernel_launch(void* const* d_in, const int* in_sizes, int n_in,
                              void* d_out, int out_size, void* d_ws, size_t ws_size,
                              hipStream_t stream) {
    const float* ego       = (const float*)d_in[0];
    const float* conv_w    = (const float*)d_in[1];
    const float* conv_b    = (const float*)d_in[2];
    const float* in_scale  = (const float*)d_in[3];
    const float* out_scale = (const float*)d_in[4];
    const float* off_w     = (const float*)d_in[5];
    const float* off_b     = (const float*)d_in[6];
    const float* aw_w      = (const float*)d_in[7];
    const float* aw_b      = (const float*)d_in[8];
    const float* vp_w      = (const float*)d_in[9];
    const float* vp_b      = (const float*)d_in[10];
    const float* op_w      = (const float*)d_in[11];
    const float* op_b      = (const float*)d_in[12];
    float* out = (float*)d_out;

    float* qf       = (float*)d_ws;                    // MM*256 f32
    float* scores   = qf + (size_t)MM * CCH;           // MM*96 f32
    float* pe       = scores + (size_t)MM * 96;        // HWW*256 f32
    float* bias_cat = pe + (size_t)HWW * CCH;          // 4*96
    short* ktb      = (short*)(bias_cat + 4 * 96);     // MM*256 bf16
    short* qb       = ktb + (size_t)MM * CCH;
    short* vb16     = qb + (size_t)MM * CCH;
    short* attnb    = vb16 + (size_t)MM * CCH;
    short* wt_big   = attnb + (size_t)MM * CCH;        // 9*256*256 bf16
    short* wt_offaw = wt_big + (size_t)9 * KK * CCH;   // 4*96*256 bf16

    pe_table_kernel<<<HWW * 128 / 256, 256, 0, stream>>>(out_scale, pe);
    convert_big_w<<<dim3(8, 8, 9), dim3(32, 8), 0, stream>>>(conv_w, vp_w, op_w, wt_big);
    convert_offaw_w<<<dim3(8, 3, 4), dim3(32, 8), 0, stream>>>(
        off_w, aw_w, off_b, aw_b, wt_offaw, bias_cat);
    transpose_pe_kernel<<<dim3(8, 512, 2), dim3(32, 8), 0, stream>>>(ego, in_scale, ktb);

    // q0 = (key_tok @ conv_w + conv_b) + pe   (out0 never materialized)
    mfma_gemm<128, 64, 64, false, 1><<<dim3(2, 256), 256, 0, stream>>>(
        ktb, wt_big, conv_b, nullptr, pe, qf, qb, CCH);

    for (int l = 0; l < 4; ++l) {
        // v (bf16) = key_tok @ vp_w + vp_b
        mfma_gemm<128, 64, 64, false, 2><<<dim3(2, 256), 256, 0, stream>>>(
            ktb, wt_big + (size_t)(1 + l) * KK * CCH, vp_b + l * CCH,
            nullptr, pe, nullptr, vb16, CCH);
        // scores = q @ [off_w | aw_w] + [off_b | aw_b]   (N = 96)
        mfma_gemm<96, 64, 48, false, 0><<<dim3(1, 256), 256, 0, stream>>>(
            qb, wt_offaw + (size_t)l * 96 * KK, bias_cat + l * 96,
            nullptr, pe, scores, nullptr, 96);
        // attn (bf16) = deformable sampling with inline softmax
        deform_kernel<<<MM * NHH / 32, 256, 0, stream>>>(vb16, scores, attnb);
        // out = attn @ op_w + op_b + q ; l<3: q' = out + pe (in-place qf/qb)
        if (l < 3) {
            mfma_gemm<128, 64, 64, true, 1><<<dim3(2, 256), 256, 0, stream>>>(
                attnb, wt_big + (size_t)(5 + l) * KK * CCH, op_b + l * CCH,
                qf, pe, qf, qb, CCH);
        } else {
            mfma_gemm<128, 64, 64, true, 0><<<dim3(2, 256), 256, 0, stream>>>(
                attnb, wt_big + (size_t)(5 + l) * KK * CCH, op_b + l * CCH,
                qf, pe, out, nullptr, CCH);
        }
    }
}